// Round 1
// 598.205 us; speedup vs baseline: 1.1045x; 1.1045x over previous
//
#include <hip/hip_runtime.h>
#include <hip/hip_bf16.h>

// S = (Q K^T)/32 * mask (multiplicative), attn = softmax(S), ctx = attn * K.
// d_out = ctx (8*2048*1024 f32) ++ attn (8*2048*2048 f32).
// R3: both GEMMs ported to a 256x256 (BK=64) 8-wave, 4-phase-per-K-tile pipeline
// with counted vmcnt (never 0 in steady state), chunk-XOR LDS swizzle applied as
// pre-swizzled global source + swizzled ds_read, raw s_barrier pairs, setprio
// around MFMA clusters, and XCD-bijective block swizzle.

typedef __attribute__((ext_vector_type(8))) short bf16x8;
typedef __attribute__((ext_vector_type(4))) float f32x4;
typedef __attribute__((ext_vector_type(4))) unsigned u32x4;
typedef __attribute__((ext_vector_type(2))) unsigned u32x2;

constexpr int BATCH = 8;
constexpr int LQ    = 2048;
constexpr int LKK   = 2048;
constexpr int DH    = 1024;
constexpr float SCALE = 0.03125f;   // 1/sqrt(1024)

#define GAS(p) ((const __attribute__((address_space(1))) void*)(p))
#define LAS(p) ((__attribute__((address_space(3))) void*)(p))

// round-half-up fp32->bf16 pair pack (2 adds + v_perm)
__device__ __forceinline__ unsigned pack_bf16x2(float x0, float x1) {
    unsigned a = __builtin_bit_cast(unsigned, x0) + 0x8000u;
    unsigned b = __builtin_bit_cast(unsigned, x1) + 0x8000u;
    return __builtin_amdgcn_perm(b, a, 0x07060302u);  // mem order: x0.hi16, x1.hi16
}

// ---------------- prep: Q,K fp32 -> bf16 (row-major, same layout) ----------------
__global__ __launch_bounds__(256)
void cvt_kernel(const float* __restrict__ Q, const float* __restrict__ K,
                unsigned short* __restrict__ Qb, unsigned short* __restrict__ Kb) {
    const int bid = blockIdx.x;
    const float* src; unsigned short* dst; size_t off;
    if (bid < 4096) { src = Q; dst = Qb; off = (size_t)bid * 4096; }
    else            { src = K; dst = Kb; off = (size_t)(bid - 4096) * 4096; }
    off += (size_t)threadIdx.x * 16;
    const f32x4 a = *(const f32x4*)(src + off);
    const f32x4 b = *(const f32x4*)(src + off + 4);
    const f32x4 c = *(const f32x4*)(src + off + 8);
    const f32x4 d = *(const f32x4*)(src + off + 12);
    u32x4 v0, v1;
    v0[0] = pack_bf16x2(a[0], a[1]); v0[1] = pack_bf16x2(a[2], a[3]);
    v0[2] = pack_bf16x2(b[0], b[1]); v0[3] = pack_bf16x2(b[2], b[3]);
    v1[0] = pack_bf16x2(c[0], c[1]); v1[1] = pack_bf16x2(c[2], c[3]);
    v1[2] = pack_bf16x2(d[0], d[1]); v1[3] = pack_bf16x2(d[2], d[3]);
    *(u32x4*)(dst + off)     = v0;
    *(u32x4*)(dst + off + 8) = v1;
}

// ---------------- prep: K fp32 -> K^T bf16, KT[b][d][k] (register 4x4 transpose) ----
__global__ __launch_bounds__(256)
void kt_kernel(const float* __restrict__ K, unsigned short* __restrict__ KT) {
    const int b  = blockIdx.z;
    const int k0 = blockIdx.y * 64;
    const int d0 = blockIdx.x * 64;
    const int t  = threadIdx.x;
    const int k4 = (t >> 4) * 4;
    const int d4 = (t & 15) * 4;
    f32x4 rk[4];
    const float* Kp = K + ((size_t)b * LKK + k0 + k4) * DH + d0 + d4;
#pragma unroll
    for (int j = 0; j < 4; ++j) rk[j] = *(const f32x4*)(Kp + (size_t)j * DH);
    unsigned short* Tp = KT + ((size_t)b * DH + d0 + d4) * LKK + k0 + k4;
#pragma unroll
    for (int c = 0; c < 4; ++c) {
        u32x2 w;
        w[0] = pack_bf16x2(rk[0][c], rk[1][c]);
        w[1] = pack_bf16x2(rk[2][c], rk[3][c]);
        *(u32x2*)(Tp + (size_t)c * LKK) = w;
    }
}

// ================= 8-phase 256x256 BK=64 pipelined mainloop ========================
// LDS per matrix: [2 parity][2 khalf][256 rows][32 k bf16] = 64 KiB (A) + 64 KiB (B).
// Half-tiles per K-tile, issue order: h=0:A-k0, 1:B-k0, 2:A-k1, 3:B-k1.
// Phase q of tile T (q=0..3): kh=q>>1, mhalf=q&1.
//   reads: A frags rows wm+(mhalf*4+mf)*16, khalf kh; B frags (only q even) khalf kh.
//   stage: half idx I = 4T+q+6 (6-half lookahead -> 1.5 tiles ahead).
//   WAR: overwrite of region (parity,kh) issues >=1 phase after its last read,
//        with the phase-end barrier in between.
//   RAW: vmcnt(4) at q==3 leaves only the 2 newest halves (tile T+2) in flight ->
//        tile T+1 fully landed before its first read. Drain vmcnt(0) only at T=NT-2.
// Chunk swizzle: 16B chunk c of row r stored at slot c ^ ((r>>1)&3); reader picks
// slot quad ^ ((lrow>>1)&3). Write side realized by pre-swizzling the GLOBAL source
// column (global_load_lds dest stays linear: wave-uniform base + lane*16).
template<int LDA, int LDB, int NT>
__device__ __forceinline__ void gemm8_mainloop(
    const unsigned short* __restrict__ Ab,   // block A panel (row0,k0)
    const unsigned short* __restrict__ Bb,   // block B panel (row0,k0)
    unsigned short* lA, unsigned short* lB,
    f32x4 (&acc)[8][4])
{
    const int tid  = threadIdx.x;
    const int lane = tid & 63;
    const int wid  = tid >> 6;
    const int wm   = (wid & 1) * 128;
    const int wn   = (wid >> 1) * 64;
    const int lrow = lane & 15;
    const int quad = lane >> 4;
    const int slotsw = (quad ^ ((lrow >> 1) & 3)) * 8;     // shorts, swizzled read slot

    // staging: thread owns rows wid*32+(lane>>2) and +16; 16B chunk (lane&3),
    // source column pre-swizzled so linear LDS landing == swizzled layout.
    const int srow0 = wid * 32 + (lane >> 2);
    const int srow1 = srow0 + 16;
    const int sc    = ((lane & 3) ^ ((lane >> 3) & 3)) * 8; // elements

    auto stage = [&](int I) {
        const int tile = I >> 2;
        const int h    = I & 3;
        const int kh   = h >> 1;
        const int kb   = tile * 64 + kh * 32 + sc;
        const unsigned short* s = (h & 1) ? Bb : Ab;
        const int ld            = (h & 1) ? LDB : LDA;
        unsigned short* d = ((h & 1) ? lB : lA)
                          + (tile & 1) * 16384 + kh * 8192 + wid * 1024;
        __builtin_amdgcn_global_load_lds(GAS(s + (size_t)srow0 * ld + kb), LAS(d),       16, 0, 0);
        __builtin_amdgcn_global_load_lds(GAS(s + (size_t)srow1 * ld + kb), LAS(d + 512), 16, 0, 0);
    };

#pragma unroll
    for (int i = 0; i < 8; ++i)
#pragma unroll
        for (int j = 0; j < 4; ++j) acc[i][j] = (f32x4){0.f, 0.f, 0.f, 0.f};

    // prologue: tile0 complete + tile1 halves 0,1 in flight
#pragma unroll
    for (int I = 0; I < 6; ++I) stage(I);
    asm volatile("s_waitcnt vmcnt(4)" ::: "memory");
    __builtin_amdgcn_s_barrier();

    for (int T = 0; T < NT; ++T) {
        const int par = (T & 1) * 16384;
        bf16x8 bfr[4];
#pragma unroll
        for (int q = 0; q < 4; ++q) {
            const int kh = (q >> 1) * 8192;
            const int mh = (q & 1) * 4;
            if ((q & 1) == 0) {
#pragma unroll
                for (int nf = 0; nf < 4; ++nf)
                    bfr[nf] = *(const bf16x8*)&lB[par + kh + (wn + nf * 16 + lrow) * 32 + slotsw];
            }
            bf16x8 af[4];
#pragma unroll
            for (int mf = 0; mf < 4; ++mf)
                af[mf] = *(const bf16x8*)&lA[par + kh + (wm + (mh + mf) * 16 + lrow) * 32 + slotsw];

            if (4 * T + q + 6 < 4 * NT) stage(4 * T + q + 6);

            __builtin_amdgcn_s_barrier();
            __builtin_amdgcn_s_setprio(1);
#pragma unroll
            for (int mf = 0; mf < 4; ++mf)
#pragma unroll
                for (int nf = 0; nf < 4; ++nf)
                    acc[mh + mf][nf] = __builtin_amdgcn_mfma_f32_16x16x32_bf16(
                        af[mf], bfr[nf], acc[mh + mf][nf], 0, 0, 0);
            __builtin_amdgcn_s_setprio(0);
            if (q == 3) {
                if (T < NT - 2)       asm volatile("s_waitcnt vmcnt(4)" ::: "memory");
                else if (T == NT - 2) asm volatile("s_waitcnt vmcnt(0)" ::: "memory");
            }
            __builtin_amdgcn_s_barrier();
        }
    }
}

// ---------------- GEMM1: S[b,q,n] = (Qb[q,:] . Kb[n,:]) * SCALE * M ----------------
__global__ __launch_bounds__(512, 2)
void qk8(const unsigned short* __restrict__ Qb, const unsigned short* __restrict__ Kb,
         const float* __restrict__ M, float* __restrict__ S) {
    __shared__ __align__(16) unsigned short lA[32768];
    __shared__ __align__(16) unsigned short lB[32768];

    // 512 blocks: XCD-bijective swizzle (512 % 8 == 0); each XCD chunk = one batch.
    const int l   = blockIdx.x;
    const int swz = (l & 7) * 64 + (l >> 3);
    const int b   = swz >> 6;
    const int my  = (swz >> 3) & 7;
    const int nx  = swz & 7;
    const int q0  = my * 256;
    const int n0  = nx * 256;

    const unsigned short* Ap = Qb + ((size_t)b * LQ  + q0) * DH;
    const unsigned short* Bp = Kb + ((size_t)b * LKK + n0) * DH;

    f32x4 acc[8][4];
    gemm8_mainloop<DH, DH, DH / 64>(Ap, Bp, lA, lB, acc);

    const int lane = threadIdx.x & 63;
    const int wid  = threadIdx.x >> 6;
    const int wm   = (wid & 1) * 128;
    const int wn   = (wid >> 1) * 64;
    const int lrow = lane & 15;
    const int quad = lane >> 4;

    // C/D layout: col = lane&15, row = quad*4 + r (m89/m91)
    const size_t base = (size_t)b * LQ * LKK;
#pragma unroll
    for (int mf = 0; mf < 8; ++mf) {
#pragma unroll
        for (int r = 0; r < 4; ++r) {
            const int row = q0 + wm + mf * 16 + quad * 4 + r;
            const size_t rb = base + (size_t)row * LKK;
#pragma unroll
            for (int nf = 0; nf < 4; ++nf) {
                const int col = n0 + wn + nf * 16 + lrow;
                S[rb + col] = acc[mf][nf][r] * SCALE * M[rb + col];
            }
        }
    }
}

// ---------------- softmax rows of S in place; bf16 copy for pk -------
__global__ __launch_bounds__(256)
void softmax_kernel(float* __restrict__ A, unsigned short* __restrict__ ab) {
    float* p = A + (size_t)blockIdx.x * LKK;
    const int tid  = threadIdx.x;
    const int lane = tid & 63;
    const int wid  = tid >> 6;

    f32x4 v0 = *(const f32x4*)(p + tid * 8);
    f32x4 v1 = *(const f32x4*)(p + tid * 8 + 4);

    float m = v0[0];
#pragma unroll
    for (int i = 1; i < 4; ++i) m = fmaxf(m, v0[i]);
#pragma unroll
    for (int i = 0; i < 4; ++i) m = fmaxf(m, v1[i]);
#pragma unroll
    for (int o = 32; o >= 1; o >>= 1) m = fmaxf(m, __shfl_xor(m, o, 64));

    __shared__ float red[8];
    if (lane == 0) red[wid] = m;
    __syncthreads();
    m = fmaxf(fmaxf(red[0], red[1]), fmaxf(red[2], red[3]));

    float s = 0.f;
    f32x4 e0, e1;
#pragma unroll
    for (int i = 0; i < 4; ++i) { e0[i] = __expf(v0[i] - m); s += e0[i]; }
#pragma unroll
    for (int i = 0; i < 4; ++i) { e1[i] = __expf(v1[i] - m); s += e1[i]; }
#pragma unroll
    for (int o = 32; o >= 1; o >>= 1) s += __shfl_xor(s, o, 64);
    if (lane == 0) red[4 + wid] = s;
    __syncthreads();
    const float inv = 1.f / (red[4] + red[5] + red[6] + red[7]);

#pragma unroll
    for (int i = 0; i < 4; ++i) { e0[i] *= inv; e1[i] *= inv; }
    *(f32x4*)(p + tid * 8)     = e0;
    *(f32x4*)(p + tid * 8 + 4) = e1;

    if (ab) {
        u32x4 w;
        w[0] = pack_bf16x2(e0[0], e0[1]); w[1] = pack_bf16x2(e0[2], e0[3]);
        w[2] = pack_bf16x2(e1[0], e1[1]); w[3] = pack_bf16x2(e1[2], e1[3]);
        *(u32x4*)(ab + (size_t)blockIdx.x * LKK + tid * 8) = w;
    }
}

// ---------------- GEMM2: ctx = attn_bf * KT_bf (both pre-packed bf16) ---------
__global__ __launch_bounds__(512, 2)
void pk8(const unsigned short* __restrict__ Pb, const unsigned short* __restrict__ KT,
         float* __restrict__ C) {
    __shared__ __align__(16) unsigned short lA[32768];
    __shared__ __align__(16) unsigned short lB[32768];

    // 256 blocks: b(8) x my(8) x nx(4), XCD-bijective swizzle (256 % 8 == 0).
    const int l   = blockIdx.x;
    const int swz = (l & 7) * 32 + (l >> 3);
    const int b   = swz >> 5;
    const int my  = (swz >> 2) & 7;
    const int nx  = swz & 3;
    const int q0  = my * 256;
    const int n0  = nx * 256;   // d offset

    const unsigned short* Ap = Pb + ((size_t)b * LQ + q0) * LKK;
    const unsigned short* Bp = KT + ((size_t)b * DH + n0) * LKK;

    f32x4 acc[8][4];
    gemm8_mainloop<LKK, LKK, LKK / 64>(Ap, Bp, lA, lB, acc);

    const int lane = threadIdx.x & 63;
    const int wid  = threadIdx.x >> 6;
    const int wm   = (wid & 1) * 128;
    const int wn   = (wid >> 1) * 64;
    const int lrow = lane & 15;
    const int quad = lane >> 4;

    const size_t cb = (size_t)b * LQ * DH;
#pragma unroll
    for (int mf = 0; mf < 8; ++mf) {
#pragma unroll
        for (int r = 0; r < 4; ++r) {
            const int row = q0 + wm + mf * 16 + quad * 4 + r;
            const size_t rbase = cb + (size_t)row * DH;
#pragma unroll
            for (int nf = 0; nf < 4; ++nf)
                C[rbase + n0 + wn + nf * 16 + lrow] = acc[mf][nf][r];
        }
    }
}

// ---------------- GEMM2 fallback (R1, 128^2 2-phase): inline fp32->bf16 ------------
constexpr int BM = 128, BN = 128, TK = 32;
constexpr int LDSS = 40;
__global__ __launch_bounds__(256, 2)
void pk_kernel(const float* __restrict__ P, const float* __restrict__ K,
               float* __restrict__ C) {
    __shared__ unsigned short lA[BM * LDSS];
    __shared__ unsigned short lB[BN * LDSS];

    const int b  = blockIdx.z;
    const int q0 = blockIdx.y * BM;
    const int n0 = blockIdx.x * BN;
    const float* Pp = P + (size_t)b * LQ * LKK + (size_t)q0 * LKK;
    const float* Kb = K + (size_t)b * LKK * DH;

    const int tid  = threadIdx.x;
    const int lane = tid & 63;
    const int wid  = tid >> 6;
    const int wm   = (wid & 1) * 64;
    const int wn   = (wid >> 1) * 64;
    const int lrow = lane & 15;
    const int quad = lane >> 4;

    f32x4 acc[4][4];
#pragma unroll
    for (int i = 0; i < 4; ++i)
#pragma unroll
        for (int j = 0; j < 4; ++j) acc[i][j] = (f32x4){0.f, 0.f, 0.f, 0.f};

    const int srow = tid >> 3;
    const int skq  = (tid & 7) << 2;
    const int tdb  = tid >> 3;
    const int tkb  = tid & 7;

    for (int k0 = 0; k0 < LKK; k0 += TK) {
        __syncthreads();
#pragma unroll
        for (int i = 0; i < 4; ++i) {
            const int row = i * 32 + srow;
            const f32x4 va = *(const f32x4*)(Pp + (size_t)row * LKK + k0 + skq);
            unsigned* pa = (unsigned*)&lA[row * LDSS + skq];
            pa[0] = pack_bf16x2(va[0], va[1]);
            pa[1] = pack_bf16x2(va[2], va[3]);
        }
        f32x4 rk[4];
#pragma unroll
        for (int j = 0; j < 4; ++j)
            rk[j] = *(const f32x4*)(Kb + (size_t)(k0 + tkb * 4 + j) * DH + n0 + tdb * 4);
#pragma unroll
        for (int c = 0; c < 4; ++c) {
            unsigned* pb = (unsigned*)&lB[(tdb * 4 + c) * LDSS + tkb * 4];
            pb[0] = pack_bf16x2(rk[0][c], rk[1][c]);
            pb[1] = pack_bf16x2(rk[2][c], rk[3][c]);
        }
        __syncthreads();

        bf16x8 af[4], bfr[4];
#pragma unroll
        for (int i = 0; i < 4; ++i) {
            af[i]  = *(const bf16x8*)&lA[(wm + i * 16 + lrow) * LDSS + quad * 8];
            bfr[i] = *(const bf16x8*)&lB[(wn + i * 16 + lrow) * LDSS + quad * 8];
        }
#pragma unroll
        for (int i = 0; i < 4; ++i)
#pragma unroll
            for (int j = 0; j < 4; ++j)
                acc[i][j] = __builtin_amdgcn_mfma_f32_16x16x32_bf16(af[i], bfr[j], acc[i][j], 0, 0, 0);
    }

    const size_t cb = (size_t)b * LQ * DH;
#pragma unroll
    for (int i = 0; i < 4; ++i) {
#pragma unroll
        for (int r = 0; r < 4; ++r) {
            const int row = q0 + wm + i * 16 + quad * 4 + r;
            const size_t rbase = cb + (size_t)row * DH;
#pragma unroll
            for (int j = 0; j < 4; ++j)
                C[rbase + n0 + wn + j * 16 + lrow] = acc[i][j][r];
        }
    }
}

extern "C" void kernel_launch(void* const* d_in, const int* in_sizes, int n_in,
                              void* d_out, int out_size, void* d_ws, size_t ws_size,
                              hipStream_t stream) {
    const float* Q = (const float*)d_in[0];
    const float* K = (const float*)d_in[1];
    const float* M = (const float*)d_in[2];

    constexpr size_t QEL  = (size_t)BATCH * LQ * DH;    // 16,777,216 (ctx elems)
    constexpr size_t AEL  = (size_t)BATCH * LQ * LKK;   // 33,554,432 (attn elems)
    constexpr size_t KTEL = (size_t)BATCH * DH * LKK;   // 16,777,216

    float* ctx  = (float*)d_out;
    float* attn = ctx + QEL;

    // bf16 Q/K scratch inside the (not-yet-written) ctx region: 2*QEL*2B == QEL*4B.
    unsigned short* Qb = (unsigned short*)ctx;
    unsigned short* Kb = Qb + QEL;

    const bool wsOK = ws_size >= (KTEL + AEL) * sizeof(unsigned short);
    unsigned short* KT = (unsigned short*)d_ws;
    unsigned short* ab = KT + KTEL;

    cvt_kernel<<<dim3(8192), 256, 0, stream>>>(Q, K, Qb, Kb);
    if (wsOK)
        kt_kernel<<<dim3(DH / 64, LKK / 64, BATCH), 256, 0, stream>>>(K, KT);
    qk8<<<dim3(BATCH * (LQ / 256) * (LKK / 256)), 512, 0, stream>>>(Qb, Kb, M, attn);
    softmax_kernel<<<dim3(BATCH * LQ), 256, 0, stream>>>(attn, wsOK ? ab : nullptr);
    if (wsOK)
        pk8<<<dim3(BATCH * (LQ / 256) * (DH / 256)), 512, 0, stream>>>(ab, KT, ctx);
    else
        pk_kernel<<<dim3(DH / BN, LQ / BM, BATCH), 256, 0, stream>>>(attn, K, ctx);
}

// Round 2
// 562.797 us; speedup vs baseline: 1.1739x; 1.0629x over previous
//
#include <hip/hip_runtime.h>
#include <hip/hip_bf16.h>

// S = (Q K^T)/32 * mask (multiplicative), attn = softmax(S), ctx = attn * K.
// d_out = ctx (8*2048*1024 f32) ++ attn (8*2048*2048 f32).
// R4: R3's 256x256 BK=64 4-phase pipeline, but fragment loads switched to
// inline-asm ds_read_b128 (+ explicit lgkmcnt(0) + sched_barrier(0), rule 18)
// so the compiler cannot insert s_waitcnt vmcnt(0) before them and the counted
// vmcnt(4) steady-state pipeline actually engages.

typedef __attribute__((ext_vector_type(8))) short bf16x8;
typedef __attribute__((ext_vector_type(4))) float f32x4;
typedef __attribute__((ext_vector_type(4))) unsigned u32x4;
typedef __attribute__((ext_vector_type(2))) unsigned u32x2;

constexpr int BATCH = 8;
constexpr int LQ    = 2048;
constexpr int LKK   = 2048;
constexpr int DH    = 1024;
constexpr float SCALE = 0.03125f;   // 1/sqrt(1024)

#define GAS(p) ((const __attribute__((address_space(1))) void*)(p))
#define LAS(p) ((__attribute__((address_space(3))) void*)(p))

// 32-bit LDS byte offset of a generic pointer into __shared__
__device__ __forceinline__ unsigned lds_addr(const unsigned short* p) {
    return (unsigned)(unsigned long long)
        (const __attribute__((address_space(3))) unsigned short*)p;
}

// opaque LDS read: compiler cannot attach vmcnt waits to it (rule 18: caller
// must s_waitcnt lgkmcnt + sched_barrier(0) before consuming the result).
__device__ __forceinline__ bf16x8 dsr_b128(unsigned off) {
    bf16x8 r;
    asm volatile("ds_read_b128 %0, %1" : "=v"(r) : "v"(off));
    return r;
}

// round-half-up fp32->bf16 pair pack (2 adds + v_perm)
__device__ __forceinline__ unsigned pack_bf16x2(float x0, float x1) {
    unsigned a = __builtin_bit_cast(unsigned, x0) + 0x8000u;
    unsigned b = __builtin_bit_cast(unsigned, x1) + 0x8000u;
    return __builtin_amdgcn_perm(b, a, 0x07060302u);  // mem order: x0.hi16, x1.hi16
}

// ---------------- prep: Q,K fp32 -> bf16 (row-major, same layout) ----------------
__global__ __launch_bounds__(256)
void cvt_kernel(const float* __restrict__ Q, const float* __restrict__ K,
                unsigned short* __restrict__ Qb, unsigned short* __restrict__ Kb) {
    const int bid = blockIdx.x;
    const float* src; unsigned short* dst; size_t off;
    if (bid < 4096) { src = Q; dst = Qb; off = (size_t)bid * 4096; }
    else            { src = K; dst = Kb; off = (size_t)(bid - 4096) * 4096; }
    off += (size_t)threadIdx.x * 16;
    const f32x4 a = *(const f32x4*)(src + off);
    const f32x4 b = *(const f32x4*)(src + off + 4);
    const f32x4 c = *(const f32x4*)(src + off + 8);
    const f32x4 d = *(const f32x4*)(src + off + 12);
    u32x4 v0, v1;
    v0[0] = pack_bf16x2(a[0], a[1]); v0[1] = pack_bf16x2(a[2], a[3]);
    v0[2] = pack_bf16x2(b[0], b[1]); v0[3] = pack_bf16x2(b[2], b[3]);
    v1[0] = pack_bf16x2(c[0], c[1]); v1[1] = pack_bf16x2(c[2], c[3]);
    v1[2] = pack_bf16x2(d[0], d[1]); v1[3] = pack_bf16x2(d[2], d[3]);
    *(u32x4*)(dst + off)     = v0;
    *(u32x4*)(dst + off + 8) = v1;
}

// ---------------- prep: K fp32 -> K^T bf16, KT[b][d][k] (register 4x4 transpose) ----
__global__ __launch_bounds__(256)
void kt_kernel(const float* __restrict__ K, unsigned short* __restrict__ KT) {
    const int b  = blockIdx.z;
    const int k0 = blockIdx.y * 64;
    const int d0 = blockIdx.x * 64;
    const int t  = threadIdx.x;
    const int k4 = (t >> 4) * 4;
    const int d4 = (t & 15) * 4;
    f32x4 rk[4];
    const float* Kp = K + ((size_t)b * LKK + k0 + k4) * DH + d0 + d4;
#pragma unroll
    for (int j = 0; j < 4; ++j) rk[j] = *(const f32x4*)(Kp + (size_t)j * DH);
    unsigned short* Tp = KT + ((size_t)b * DH + d0 + d4) * LKK + k0 + k4;
#pragma unroll
    for (int c = 0; c < 4; ++c) {
        u32x2 w;
        w[0] = pack_bf16x2(rk[0][c], rk[1][c]);
        w[1] = pack_bf16x2(rk[2][c], rk[3][c]);
        *(u32x2*)(Tp + (size_t)c * LKK) = w;
    }
}

// ================= 8-phase 256x256 BK=64 pipelined mainloop ========================
// LDS per matrix: [2 parity][2 khalf][256 rows][32 k bf16] = 64 KiB (A) + 64 KiB (B).
// Half-tiles per K-tile, issue order: h=0:A-k0, 1:B-k0, 2:A-k1, 3:B-k1.
// Phase q of tile T (q=0..3): kh=q>>1, mhalf=q&1.
//   reads: A frags rows wm+(mhalf*4+mf)*16, khalf kh; B frags (only q even) khalf kh.
//   stage: half idx I = 4T+q+6 (6-half lookahead -> 1.5 tiles ahead).
//   WAR: every wave drains its ds_reads (lgkmcnt(0)) before reaching the phase-end
//        barrier; overwrites of a region are issued >=1 phase-end barrier later.
//   RAW: vmcnt(4) at q==3 leaves only the 2 newest halves (tile T+2) in flight ->
//        tile T+1 fully landed before its first read. Drain vmcnt(0) only at T=NT-2.
// Chunk swizzle: 16B chunk c of row r stored at slot c ^ ((r>>1)&3); reader picks
// slot quad ^ ((lrow>>1)&3). Write side realized by pre-swizzling the GLOBAL source
// column (global_load_lds dest stays linear: wave-uniform base + lane*16).
template<int LDA, int LDB, int NT>
__device__ __forceinline__ void gemm8_mainloop(
    const unsigned short* __restrict__ Ab,   // block A panel (row0,k0)
    const unsigned short* __restrict__ Bb,   // block B panel (row0,k0)
    unsigned short* lA, unsigned short* lB,
    f32x4 (&acc)[8][4])
{
    const int tid  = threadIdx.x;
    const int lane = tid & 63;
    const int wid  = tid >> 6;
    const int wm   = (wid & 1) * 128;
    const int wn   = (wid >> 1) * 64;
    const int lrow = lane & 15;
    const int quad = lane >> 4;
    const int slotsw = (quad ^ ((lrow >> 1) & 3)) * 8;     // shorts, swizzled read slot

    // staging: thread owns rows wid*32+(lane>>2) and +16; 16B chunk (lane&3),
    // source column pre-swizzled so linear LDS landing == swizzled layout.
    const int srow0 = wid * 32 + (lane >> 2);
    const int srow1 = srow0 + 16;
    const int sc    = ((lane & 3) ^ ((lane >> 3) & 3)) * 8; // elements

    auto stage = [&](int I) {
        const int tile = I >> 2;
        const int h    = I & 3;
        const int kh   = h >> 1;
        const int kb   = tile * 64 + kh * 32 + sc;
        const unsigned short* s = (h & 1) ? Bb : Ab;
        const int ld            = (h & 1) ? LDB : LDA;
        unsigned short* d = ((h & 1) ? lB : lA)
                          + (tile & 1) * 16384 + kh * 8192 + wid * 1024;
        __builtin_amdgcn_global_load_lds(GAS(s + (size_t)srow0 * ld + kb), LAS(d),       16, 0, 0);
        __builtin_amdgcn_global_load_lds(GAS(s + (size_t)srow1 * ld + kb), LAS(d + 512), 16, 0, 0);
    };

#pragma unroll
    for (int i = 0; i < 8; ++i)
#pragma unroll
        for (int j = 0; j < 4; ++j) acc[i][j] = (f32x4){0.f, 0.f, 0.f, 0.f};

    // prologue: tile0 complete + tile1 halves 0,1 in flight
#pragma unroll
    for (int I = 0; I < 6; ++I) stage(I);
    asm volatile("s_waitcnt vmcnt(4)" ::: "memory");
    __builtin_amdgcn_s_barrier();

    for (int T = 0; T < NT; ++T) {
        const int par = (T & 1) * 16384;
        bf16x8 bfr[4];
#pragma unroll
        for (int q = 0; q < 4; ++q) {
            const int kh = (q >> 1) * 8192;
            const int mh = (q & 1) * 4;
            if ((q & 1) == 0) {
#pragma unroll
                for (int nf = 0; nf < 4; ++nf)
                    bfr[nf] = dsr_b128(lds_addr(&lB[par + kh + (wn + nf * 16 + lrow) * 32 + slotsw]));
            }
            bf16x8 af[4];
#pragma unroll
            for (int mf = 0; mf < 4; ++mf)
                af[mf] = dsr_b128(lds_addr(&lA[par + kh + (wm + (mh + mf) * 16 + lrow) * 32 + slotsw]));

            if (4 * T + q + 6 < 4 * NT) stage(4 * T + q + 6);

            __builtin_amdgcn_s_barrier();
            asm volatile("s_waitcnt lgkmcnt(0)" ::: "memory");
            __builtin_amdgcn_sched_barrier(0);
            __builtin_amdgcn_s_setprio(1);
#pragma unroll
            for (int mf = 0; mf < 4; ++mf)
#pragma unroll
                for (int nf = 0; nf < 4; ++nf)
                    acc[mh + mf][nf] = __builtin_amdgcn_mfma_f32_16x16x32_bf16(
                        af[mf], bfr[nf], acc[mh + mf][nf], 0, 0, 0);
            __builtin_amdgcn_s_setprio(0);
            if (q == 3) {
                if (T < NT - 2)       asm volatile("s_waitcnt vmcnt(4)" ::: "memory");
                else if (T == NT - 2) asm volatile("s_waitcnt vmcnt(0)" ::: "memory");
            }
            __builtin_amdgcn_s_barrier();
        }
    }
}

// ---------------- GEMM1: S[b,q,n] = (Qb[q,:] . Kb[n,:]) * SCALE * M ----------------
__global__ __launch_bounds__(512, 2)
void qk8(const unsigned short* __restrict__ Qb, const unsigned short* __restrict__ Kb,
         const float* __restrict__ M, float* __restrict__ S) {
    __shared__ __align__(16) unsigned short lA[32768];
    __shared__ __align__(16) unsigned short lB[32768];

    // 512 blocks: XCD-bijective swizzle (512 % 8 == 0); each XCD chunk = one batch.
    const int l   = blockIdx.x;
    const int swz = (l & 7) * 64 + (l >> 3);
    const int b   = swz >> 6;
    const int my  = (swz >> 3) & 7;
    const int nx  = swz & 7;
    const int q0  = my * 256;
    const int n0  = nx * 256;

    const unsigned short* Ap = Qb + ((size_t)b * LQ  + q0) * DH;
    const unsigned short* Bp = Kb + ((size_t)b * LKK + n0) * DH;

    f32x4 acc[8][4];
    gemm8_mainloop<DH, DH, DH / 64>(Ap, Bp, lA, lB, acc);

    const int lane = threadIdx.x & 63;
    const int wid  = threadIdx.x >> 6;
    const int wm   = (wid & 1) * 128;
    const int wn   = (wid >> 1) * 64;
    const int lrow = lane & 15;
    const int quad = lane >> 4;

    // C/D layout: col = lane&15, row = quad*4 + r (m89/m91)
    const size_t base = (size_t)b * LQ * LKK;
#pragma unroll
    for (int mf = 0; mf < 8; ++mf) {
#pragma unroll
        for (int r = 0; r < 4; ++r) {
            const int row = q0 + wm + mf * 16 + quad * 4 + r;
            const size_t rb = base + (size_t)row * LKK;
#pragma unroll
            for (int nf = 0; nf < 4; ++nf) {
                const int col = n0 + wn + nf * 16 + lrow;
                S[rb + col] = acc[mf][nf][r] * SCALE * M[rb + col];
            }
        }
    }
}

// ---------------- softmax rows of S in place; bf16 copy for pk -------
__global__ __launch_bounds__(256)
void softmax_kernel(float* __restrict__ A, unsigned short* __restrict__ ab) {
    float* p = A + (size_t)blockIdx.x * LKK;
    const int tid  = threadIdx.x;
    const int lane = tid & 63;
    const int wid  = tid >> 6;

    f32x4 v0 = *(const f32x4*)(p + tid * 8);
    f32x4 v1 = *(const f32x4*)(p + tid * 8 + 4);

    float m = v0[0];
#pragma unroll
    for (int i = 1; i < 4; ++i) m = fmaxf(m, v0[i]);
#pragma unroll
    for (int i = 0; i < 4; ++i) m = fmaxf(m, v1[i]);
#pragma unroll
    for (int o = 32; o >= 1; o >>= 1) m = fmaxf(m, __shfl_xor(m, o, 64));

    __shared__ float red[8];
    if (lane == 0) red[wid] = m;
    __syncthreads();
    m = fmaxf(fmaxf(red[0], red[1]), fmaxf(red[2], red[3]));

    float s = 0.f;
    f32x4 e0, e1;
#pragma unroll
    for (int i = 0; i < 4; ++i) { e0[i] = __expf(v0[i] - m); s += e0[i]; }
#pragma unroll
    for (int i = 0; i < 4; ++i) { e1[i] = __expf(v1[i] - m); s += e1[i]; }
#pragma unroll
    for (int o = 32; o >= 1; o >>= 1) s += __shfl_xor(s, o, 64);
    if (lane == 0) red[4 + wid] = s;
    __syncthreads();
    const float inv = 1.f / (red[4] + red[5] + red[6] + red[7]);

#pragma unroll
    for (int i = 0; i < 4; ++i) { e0[i] *= inv; e1[i] *= inv; }
    *(f32x4*)(p + tid * 8)     = e0;
    *(f32x4*)(p + tid * 8 + 4) = e1;

    if (ab) {
        u32x4 w;
        w[0] = pack_bf16x2(e0[0], e0[1]); w[1] = pack_bf16x2(e0[2], e0[3]);
        w[2] = pack_bf16x2(e1[0], e1[1]); w[3] = pack_bf16x2(e1[2], e1[3]);
        *(u32x4*)(ab + (size_t)blockIdx.x * LKK + tid * 8) = w;
    }
}

// ---------------- GEMM2: ctx = attn_bf * KT_bf (both pre-packed bf16) ---------
__global__ __launch_bounds__(512, 2)
void pk8(const unsigned short* __restrict__ Pb, const unsigned short* __restrict__ KT,
         float* __restrict__ C) {
    __shared__ __align__(16) unsigned short lA[32768];
    __shared__ __align__(16) unsigned short lB[32768];

    // 256 blocks: b(8) x my(8) x nx(4), XCD-bijective swizzle (256 % 8 == 0).
    const int l   = blockIdx.x;
    const int swz = (l & 7) * 32 + (l >> 3);
    const int b   = swz >> 5;
    const int my  = (swz >> 2) & 7;
    const int nx  = swz & 3;
    const int q0  = my * 256;
    const int n0  = nx * 256;   // d offset

    const unsigned short* Ap = Pb + ((size_t)b * LQ + q0) * LKK;
    const unsigned short* Bp = KT + ((size_t)b * DH + n0) * LKK;

    f32x4 acc[8][4];
    gemm8_mainloop<LKK, LKK, LKK / 64>(Ap, Bp, lA, lB, acc);

    const int lane = threadIdx.x & 63;
    const int wid  = threadIdx.x >> 6;
    const int wm   = (wid & 1) * 128;
    const int wn   = (wid >> 1) * 64;
    const int lrow = lane & 15;
    const int quad = lane >> 4;

    const size_t cb = (size_t)b * LQ * DH;
#pragma unroll
    for (int mf = 0; mf < 8; ++mf) {
#pragma unroll
        for (int r = 0; r < 4; ++r) {
            const int row = q0 + wm + mf * 16 + quad * 4 + r;
            const size_t rbase = cb + (size_t)row * DH;
#pragma unroll
            for (int nf = 0; nf < 4; ++nf)
                C[rbase + n0 + wn + nf * 16 + lrow] = acc[mf][nf][r];
        }
    }
}

// ---------------- GEMM2 fallback (R1, 128^2 2-phase): inline fp32->bf16 ------------
constexpr int BM = 128, BN = 128, TK = 32;
constexpr int LDSS = 40;
__global__ __launch_bounds__(256, 2)
void pk_kernel(const float* __restrict__ P, const float* __restrict__ K,
               float* __restrict__ C) {
    __shared__ unsigned short lA[BM * LDSS];
    __shared__ unsigned short lB[BN * LDSS];

    const int b  = blockIdx.z;
    const int q0 = blockIdx.y * BM;
    const int n0 = blockIdx.x * BN;
    const float* Pp = P + (size_t)b * LQ * LKK + (size_t)q0 * LKK;
    const float* Kb = K + (size_t)b * LKK * DH;

    const int tid  = threadIdx.x;
    const int lane = tid & 63;
    const int wid  = tid >> 6;
    const int wm   = (wid & 1) * 64;
    const int wn   = (wid >> 1) * 64;
    const int lrow = lane & 15;
    const int quad = lane >> 4;

    f32x4 acc[4][4];
#pragma unroll
    for (int i = 0; i < 4; ++i)
#pragma unroll
        for (int j = 0; j < 4; ++j) acc[i][j] = (f32x4){0.f, 0.f, 0.f, 0.f};

    const int srow = tid >> 3;
    const int skq  = (tid & 7) << 2;
    const int tdb  = tid >> 3;
    const int tkb  = tid & 7;

    for (int k0 = 0; k0 < LKK; k0 += TK) {
        __syncthreads();
#pragma unroll
        for (int i = 0; i < 4; ++i) {
            const int row = i * 32 + srow;
            const f32x4 va = *(const f32x4*)(Pp + (size_t)row * LKK + k0 + skq);
            unsigned* pa = (unsigned*)&lA[row * LDSS + skq];
            pa[0] = pack_bf16x2(va[0], va[1]);
            pa[1] = pack_bf16x2(va[2], va[3]);
        }
        f32x4 rk[4];
#pragma unroll
        for (int j = 0; j < 4; ++j)
            rk[j] = *(const f32x4*)(Kb + (size_t)(k0 + tkb * 4 + j) * DH + n0 + tdb * 4);
#pragma unroll
        for (int c = 0; c < 4; ++c) {
            unsigned* pb = (unsigned*)&lB[(tdb * 4 + c) * LDSS + tkb * 4];
            pb[0] = pack_bf16x2(rk[0][c], rk[1][c]);
            pb[1] = pack_bf16x2(rk[2][c], rk[3][c]);
        }
        __syncthreads();

        bf16x8 af[4], bfr[4];
#pragma unroll
        for (int i = 0; i < 4; ++i) {
            af[i]  = *(const bf16x8*)&lA[(wm + i * 16 + lrow) * LDSS + quad * 8];
            bfr[i] = *(const bf16x8*)&lB[(wn + i * 16 + lrow) * LDSS + quad * 8];
        }
#pragma unroll
        for (int i = 0; i < 4; ++i)
#pragma unroll
            for (int j = 0; j < 4; ++j)
                acc[i][j] = __builtin_amdgcn_mfma_f32_16x16x32_bf16(af[i], bfr[j], acc[i][j], 0, 0, 0);
    }

    const size_t cb = (size_t)b * LQ * DH;
#pragma unroll
    for (int i = 0; i < 4; ++i) {
#pragma unroll
        for (int r = 0; r < 4; ++r) {
            const int row = q0 + wm + i * 16 + quad * 4 + r;
            const size_t rbase = cb + (size_t)row * DH;
#pragma unroll
            for (int j = 0; j < 4; ++j)
                C[rbase + n0 + wn + j * 16 + lrow] = acc[i][j][r];
        }
    }
}

extern "C" void kernel_launch(void* const* d_in, const int* in_sizes, int n_in,
                              void* d_out, int out_size, void* d_ws, size_t ws_size,
                              hipStream_t stream) {
    const float* Q = (const float*)d_in[0];
    const float* K = (const float*)d_in[1];
    const float* M = (const float*)d_in[2];

    constexpr size_t QEL  = (size_t)BATCH * LQ * DH;    // 16,777,216 (ctx elems)
    constexpr size_t AEL  = (size_t)BATCH * LQ * LKK;   // 33,554,432 (attn elems)
    constexpr size_t KTEL = (size_t)BATCH * DH * LKK;   // 16,777,216

    float* ctx  = (float*)d_out;
    float* attn = ctx + QEL;

    // bf16 Q/K scratch inside the (not-yet-written) ctx region: 2*QEL*2B == QEL*4B.
    unsigned short* Qb = (unsigned short*)ctx;
    unsigned short* Kb = Qb + QEL;

    const bool wsOK = ws_size >= (KTEL + AEL) * sizeof(unsigned short);
    unsigned short* KT = (unsigned short*)d_ws;
    unsigned short* ab = KT + KTEL;

    cvt_kernel<<<dim3(8192), 256, 0, stream>>>(Q, K, Qb, Kb);
    if (wsOK)
        kt_kernel<<<dim3(DH / 64, LKK / 64, BATCH), 256, 0, stream>>>(K, KT);
    qk8<<<dim3(BATCH * (LQ / 256) * (LKK / 256)), 512, 0, stream>>>(Qb, Kb, M, attn);
    softmax_kernel<<<dim3(BATCH * LQ), 256, 0, stream>>>(attn, wsOK ? ab : nullptr);
    if (wsOK)
        pk8<<<dim3(BATCH * (LQ / 256) * (DH / 256)), 512, 0, stream>>>(ab, KT, ctx);
    else
        pk_kernel<<<dim3(DH / BN, LQ / BM, BATCH), 256, 0, stream>>>(attn, K, ctx);
}